// Round 11
// baseline (85.665 us; speedup 1.0000x reference)
//
#include <hip/hip_runtime.h>

// FBPinn 1D, NW=16 windows, MLP 1->64->64->64->1 (tanh), sigmoid windows.
// pass2 = MFMA v_mfma_f32_16x16x32_f16 (all lane mappings HW-verified):
//   C/D: col=lane&15, row=(lane>>4)*4+reg ; A/B: m|n=lane&15, k=(lane>>4)*8+j
// R11: TWO B-tiles (32 points) per wave — A-frags & prepack amortized 2x,
//      half the waves; tanh per point unchanged (irreducible VALU).
// [R9/R10: cross-lane LDS comm needs compiler fences at DS phase
//  transitions (warp-sync UB otherwise); HW same-wave DS order suffices.]
// [R10 accounting: dur ~= pass1+pass2 + ~41us harness d_ws-poison fill +
//  ~10us memset/gaps. The fill is a fixed floor.]
// pass1: LDS-histogram bucketing (known-good since R2).

#define NW    16
#define NEUR  64
#define BLK   256
#define CAP   10240
#define CSTR  16
#define GX    64       // 64 blocks x 128 pts = 8192 slots/window
#define DSFENCE() asm volatile("" ::: "memory")

typedef _Float16 v8h __attribute__((ext_vector_type(8)));
typedef float    v4f __attribute__((ext_vector_type(4)));
typedef _Float16 h2  __attribute__((ext_vector_type(2)));
typedef unsigned v4u __attribute__((ext_vector_type(4)));

__device__ __forceinline__ float fast_tanh(float x) {
    float e = __expf(x + x);
    return 1.0f - 2.0f * __builtin_amdgcn_rcpf(e + 1.0f);
}
__device__ __forceinline__ float fast_sigmoid(float z) {
    return __builtin_amdgcn_rcpf(1.0f + __expf(-z));
}
__device__ __forceinline__ v8h zero8() {
    v8h z;
    #pragma unroll
    for (int j = 0; j < 8; ++j) z[j] = (_Float16)0.0f;
    return z;
}

__global__ __launch_bounds__(1024) void pass1_bucket(
    const float* __restrict__ x, int n,
    int* __restrict__ cnt, int* __restrict__ list,
    float* __restrict__ out) {
    __shared__ int lcnt[NW];
    __shared__ int lbase[NW];
    const int tid = threadIdx.x;
    if (tid < NW) lcnt[tid] = 0;
    __syncthreads();

    const int i = blockIdx.x * 1024 + tid;
    int w0 = -1, w1 = -1, p0 = 0, p1 = 0;
    if (i < n) {
        out[i] = 0.0f;
        float xv = x[i];
        #pragma unroll
        for (int w = 0; w < NW; ++w) {
            float lo = (w == 0)      ? 0.0f   : ((float)w - 0.125f) * 6.25f;
            float hi = (w == NW - 1) ? 100.0f : ((float)w + 1.125f) * 6.25f;
            if (lo < xv && xv < hi) {           // exact strict compares
                if (w0 < 0) w0 = w; else w1 = w;
            }
        }
        if (w0 >= 0) p0 = atomicAdd(&lcnt[w0], 1);
        if (w1 >= 0) p1 = atomicAdd(&lcnt[w1], 1);
    }
    __syncthreads();
    if (tid < NW)
        lbase[tid] = atomicAdd(&cnt[tid * CSTR], lcnt[tid]);
    __syncthreads();

    if (w0 >= 0) { int p = lbase[w0] + p0; if (p < CAP) list[w0 * CAP + p] = i; }
    if (w1 >= 0) { int p = lbase[w1] + p1; if (p < CAP) list[w1 * CAP + p] = i; }
}

__global__ __launch_bounds__(256) void pass2_mlp(
    const float* __restrict__ x,
    const float* __restrict__ W_in, const float* __restrict__ b_in,
    const float* __restrict__ W_h,  const float* __restrict__ b_h,
    const float* __restrict__ W_out, const float* __restrict__ b_out,
    const int* __restrict__ cnt, const int* __restrict__ list,
    float* __restrict__ out, int npts) {
    __shared__ _Float16 aH[16 * 512];     // [l*8+mt*2+ks] frags, 16 KB
    __shared__ _Float16 aIn[4 * 512];     // [mt] frags,           4 KB
    __shared__ _Float16 aOut[2 * 512];    // [ks] frags,           2 KB
    __shared__ float    biasH[128];       // hidden biases fp32
    __shared__ unsigned Hp[4 * 1024];     // [wid][t][k2][n16], 16 KB

    const int tid = threadIdx.x;
    const int w   = blockIdx.y;
    const int count = min(cnt[w * CSTR], GX * 128);
    if (blockIdx.x * 128 >= count) return;         // uniform: whole block

    const int lane = tid & 63;
    const int wid  = tid >> 6;
    const int n16  = lane & 15;
    const int quad = lane >> 4;

    // ---- prepack A-fragments (once per block) ----
    #pragma unroll
    for (int p = 0; p < 4; ++p) {                  // hidden: 16 frags
        int f  = wid * 4 + p;                      // f = l*8 + mt*2 + ks
        int l  = f >> 3, mt = (f >> 1) & 3, ks = f & 1;
        const float* Ws = W_h + (l * NW + w) * 4096;
        int m  = mt * 16 + n16;
        int k0 = ks * 32 + quad * 8;
        v8h a;
        #pragma unroll
        for (int j = 0; j < 8; ++j)
            a[j] = (_Float16)Ws[(k0 + j) * 64 + m];   // A[m][k]=W[k][m]
        *(v8h*)(&aH[f * 512 + lane * 8]) = a;
    }
    {   // input frags: A[m][0]=Wi[m], A[m][1]=bi[m]
        int mt = wid, m = mt * 16 + n16;
        v8h a = zero8();
        if (quad == 0) {
            a[0] = (_Float16)W_in[w * 64 + m];
            a[1] = (_Float16)b_in[w * 64 + m];
        }
        *(v8h*)(&aIn[mt * 512 + lane * 8]) = a;
    }
    if (wid < 2) {  // output frags: A[0][k]=Wo[k], rows m>0 zero
        int ks = wid;
        v8h a = zero8();
        if (n16 == 0) {
            int k0 = ks * 32 + quad * 8;
            #pragma unroll
            for (int j = 0; j < 8; ++j)
                a[j] = (_Float16)W_out[w * 64 + k0 + j];
        }
        *(v8h*)(&aOut[ks * 512 + lane * 8]) = a;
    }
    if (tid < 128)
        biasH[tid] = b_h[((tid >> 6) * NW + w) * 64 + (tid & 63)];
    __syncthreads();

    // ---- per-wave: 32 points (two 16-pt B-tiles) ----
    float lo = (w == 0)      ? 0.0f   : ((float)w - 0.125f) * 6.25f;
    float hi = (w == NW - 1) ? 100.0f : ((float)w + 1.125f) * 6.25f;
    float mean    = 0.5f * (lo + hi);
    float inv_std = 1.0f / (0.5f * (hi - lo));
    float ow0 = (float)w * 6.25f;
    float ow1 = (float)(w + 1) * 6.25f;
    float bo  = b_out[w];

    float xv[2], xn[2];
    bool  act[2];
    int   idx[2];
    #pragma unroll
    for (int t = 0; t < 2; ++t) {
        int kpt = blockIdx.x * 128 + wid * 32 + t * 16 + n16;
        act[t]  = (kpt < count) && (lane < 16);
        int kk  = (kpt < count) ? kpt : 0;
        int id  = list[w * CAP + kk];
        if ((unsigned)id >= (unsigned)npts) id = 0;   // poison guard
        idx[t] = id;
        xv[t]  = x[id];
        xn[t]  = (xv[t] - mean) * inv_std;
    }

    unsigned* HpW = Hp + wid * 1024;       // tile t at offset t*512

    // input layer: pre = Wi*xn + bi, tanh -> Hp
    {
        v8h b[2];
        #pragma unroll
        for (int t = 0; t < 2; ++t) {
            b[t] = zero8();
            if (quad == 0) { b[t][0] = (_Float16)xn[t]; b[t][1] = (_Float16)1.0f; }
        }
        #pragma unroll
        for (int mt = 0; mt < 4; ++mt) {
            v8h a = *(const v8h*)(&aIn[mt * 512 + lane * 8]);   // shared by tiles
            #pragma unroll
            for (int t = 0; t < 2; ++t) {
                v4f c = {0.0f, 0.0f, 0.0f, 0.0f};
                c = __builtin_amdgcn_mfma_f32_16x16x32_f16(a, b[t], c, 0, 0, 0);
                int k2 = mt * 8 + quad * 2;        // pair rows, m0 even
                h2 q0, q1;
                q0[0] = (_Float16)fast_tanh(c[0]);
                q0[1] = (_Float16)fast_tanh(c[1]);
                q1[0] = (_Float16)fast_tanh(c[2]);
                q1[1] = (_Float16)fast_tanh(c[3]);
                HpW[t * 512 + k2 * 16 + n16]       = __builtin_bit_cast(unsigned, q0);
                HpW[t * 512 + (k2 + 1) * 16 + n16] = __builtin_bit_cast(unsigned, q1);
            }
        }
    }
    DSFENCE();   // writes(input) -> reads(hidden0): cross-lane handoff

    // hidden layers: D = W^T*H (+bias), tanh, back to Hp
    #pragma unroll
    for (int l = 0; l < 2; ++l) {
        v4f d[2][4];
        #pragma unroll
        for (int t = 0; t < 2; ++t)
            #pragma unroll
            for (int mt = 0; mt < 4; ++mt)
                d[t][mt] = (v4f){0.0f, 0.0f, 0.0f, 0.0f};
        #pragma unroll
        for (int ks = 0; ks < 2; ++ks) {
            v8h b[2];
            #pragma unroll
            for (int t = 0; t < 2; ++t) {
                v4u bw;
                #pragma unroll
                for (int j2 = 0; j2 < 4; ++j2)
                    bw[j2] = HpW[t * 512 + (ks * 16 + quad * 4 + j2) * 16 + n16];
                b[t] = __builtin_bit_cast(v8h, bw);
            }
            #pragma unroll
            for (int mt = 0; mt < 4; ++mt) {
                v8h a = *(const v8h*)(&aH[(l * 8 + mt * 2 + ks) * 512 + lane * 8]);
                #pragma unroll
                for (int t = 0; t < 2; ++t)
                    d[t][mt] = __builtin_amdgcn_mfma_f32_16x16x32_f16(
                                   a, b[t], d[t][mt], 0, 0, 0);
            }
        }
        DSFENCE();   // reads(layer l) -> writes(layer l)
        const float* bl = biasH + l * 64;
        #pragma unroll
        for (int t = 0; t < 2; ++t) {
            #pragma unroll
            for (int mt = 0; mt < 4; ++mt) {
                int m0 = mt * 16 + quad * 4;       // even
                int k2 = m0 >> 1;
                h2 q0, q1;
                q0[0] = (_Float16)fast_tanh(d[t][mt][0] + bl[m0]);
                q0[1] = (_Float16)fast_tanh(d[t][mt][1] + bl[m0 + 1]);
                q1[0] = (_Float16)fast_tanh(d[t][mt][2] + bl[m0 + 2]);
                q1[1] = (_Float16)fast_tanh(d[t][mt][3] + bl[m0 + 3]);
                HpW[t * 512 + k2 * 16 + n16]       = __builtin_bit_cast(unsigned, q0);
                HpW[t * 512 + (k2 + 1) * 16 + n16] = __builtin_bit_cast(unsigned, q1);
            }
        }
        DSFENCE();   // writes(layer l) -> reads(next phase)
    }

    // output layer: A row0 = Wo -> e[0] on lanes 0..15 is out[n]
    {
        v4f e[2] = {{0.0f,0.0f,0.0f,0.0f}, {0.0f,0.0f,0.0f,0.0f}};
        #pragma unroll
        for (int ks = 0; ks < 2; ++ks) {
            v8h a = *(const v8h*)(&aOut[ks * 512 + lane * 8]);
            #pragma unroll
            for (int t = 0; t < 2; ++t) {
                v4u bw;
                #pragma unroll
                for (int j2 = 0; j2 < 4; ++j2)
                    bw[j2] = HpW[t * 512 + (ks * 16 + quad * 4 + j2) * 16 + n16];
                v8h b = __builtin_bit_cast(v8h, bw);
                e[t] = __builtin_amdgcn_mfma_f32_16x16x32_f16(a, b, e[t], 0, 0, 0);
            }
        }
        #pragma unroll
        for (int t = 0; t < 2; ++t) {
            float outv = e[t][0] + bo;
            float win = fast_sigmoid((xv[t] - ow0) * 2.0f) *
                        fast_sigmoid((ow1 - xv[t]) * 2.0f);
            if (act[t]) atomicAdd(&out[idx[t]], win * outv);
        }
    }
}

extern "C" void kernel_launch(void* const* d_in, const int* in_sizes, int n_in,
                              void* d_out, int out_size, void* d_ws, size_t ws_size,
                              hipStream_t stream) {
    const float* x     = (const float*)d_in[0];
    const float* W_in  = (const float*)d_in[1];
    const float* b_in  = (const float*)d_in[2];
    const float* W_h   = (const float*)d_in[3];
    const float* b_h   = (const float*)d_in[4];
    const float* W_out = (const float*)d_in[5];
    const float* b_out = (const float*)d_in[6];
    float* out = (float*)d_out;
    const int n = in_sizes[0];

    int* cnt  = (int*)d_ws;
    int* list = (int*)((char*)d_ws + 1024);

    hipMemsetAsync(cnt, 0, NW * CSTR * sizeof(int), stream);

    pass1_bucket<<<(n + 1023) / 1024, 1024, 0, stream>>>(x, n, cnt, list, out);

    dim3 grid(GX, NW);
    pass2_mlp<<<grid, BLK, 0, stream>>>(x, W_in, b_in, W_h, b_h, W_out, b_out,
                                        cnt, list, out, n);
}